// Round 17
// baseline (894.984 us; speedup 1.0000x reference)
//
#include <hip/hip_runtime.h>

#define S_TOK 8192
#define DIM   1024
#define DIM2  2048
#define OUTN  1024

typedef __bf16 bf16x8 __attribute__((ext_vector_type(8)));
typedef float  f32x4  __attribute__((ext_vector_type(4)));
typedef short  s16x8  __attribute__((ext_vector_type(8)));
typedef unsigned short u16x4 __attribute__((ext_vector_type(4)));

__device__ __forceinline__ unsigned short f2bf(float x) {
  unsigned u = __builtin_bit_cast(unsigned, x);
  u = (u + 0x7FFFu + ((u >> 16) & 1u)) >> 16;
  return (unsigned short)u;
}
__device__ __forceinline__ float bf2f(unsigned short u) {
  return __builtin_bit_cast(float, (unsigned)u << 16);
}

__device__ __forceinline__ void gld_lds16(const void* g, void* l) {
  auto* g1 = reinterpret_cast<__attribute__((address_space(1))) unsigned*>(
      (unsigned long long)g);
  auto* l3 = reinterpret_cast<__attribute__((address_space(3))) unsigned*>(
      (unsigned long long)l);
  __builtin_amdgcn_global_load_lds(g1, l3, 16, 0, 0);
}

// 128^2-kernel swizzle for [rows][64] bf16 tiles (row stride 128B).
__device__ __forceinline__ int lds_off(int idx, int k) {
  int b = (idx << 7) + (k << 1);
  b ^= ((idx ^ (idx >> 3)) & 7) << 4;
  return b;
}

// ---- merged prep: z0-2 = f32->bf16 cvt; z3 = all 4 weight transposes ----
struct PrepTab {
  const float* in[3]; unsigned short* out[3];
  const float* win[4]; unsigned short* wout[4]; int R[4]; int C[4];
};
__global__ __launch_bounds__(256) void prep_all(PrepTab t) {
  __shared__ unsigned short tl[64 * 64];
  const int tid = threadIdx.x;
  if (blockIdx.z < 3) {
    const float* in = t.in[blockIdx.z];
    unsigned short* out = t.out[blockIdx.z];
    int i = blockIdx.x * 256 + tid;
    float4 v = ((const float4*)in)[i];
    u16x4 o;
    o[0] = f2bf(v.x); o[1] = f2bf(v.y); o[2] = f2bf(v.z); o[3] = f2bf(v.w);
    *(u16x4*)(out + (size_t)i * 4) = o;
    return;
  }
  int x = blockIdx.x;
  if (x >= 4096) return;
  int wz = x >> 10, rem = x & 1023, bx = rem & 31, by = rem >> 5;
  const int R = t.R[wz], C = t.C[wz];
  const int r0 = by << 6, c0 = bx << 6;
  if (r0 >= R || c0 >= C) return;
  const float* in = t.win[wz];
  unsigned short* out = t.wout[wz];
#pragma unroll
  for (int i = 0; i < 2; ++i) {
    int ch = tid + (i << 8);
    int r = ch >> 3, c8 = (ch & 7) << 3;
    const float* p = in + (size_t)(r0 + r) * C + c0 + c8;
    float4 a = *(const float4*)p, b = *(const float4*)(p + 4);
    s16x8 w;
    w[0] = (short)f2bf(a.x); w[1] = (short)f2bf(a.y);
    w[2] = (short)f2bf(a.z); w[3] = (short)f2bf(a.w);
    w[4] = (short)f2bf(b.x); w[5] = (short)f2bf(b.y);
    w[6] = (short)f2bf(b.z); w[7] = (short)f2bf(b.w);
    int sw = ((r ^ (r >> 3)) & 7) << 3;
    *(s16x8*)&tl[(r << 6) + (c8 ^ sw)] = w;
  }
  __syncthreads();
#pragma unroll
  for (int i = 0; i < 2; ++i) {
    int ch = tid + (i << 8);
    int c = ch >> 3, r8 = (ch & 7) << 3;
    s16x8 w;
#pragma unroll
    for (int j = 0; j < 8; ++j) {
      int rr = r8 + j;
      w[j] = (short)tl[(rr << 6) + (c ^ (((rr ^ (rr >> 3)) & 7) << 3))];
    }
    *(s16x8*)(out + (size_t)(c0 + c) * R + r0 + r8) = w;
  }
}

// Softmax over the ROW axis (2048 feats) of T [2048, S_TOK], per column, in place.
struct SmTab { unsigned short* T[6]; };
__global__ __launch_bounds__(512) void softmax_cols(SmTab tab) {
  unsigned short* T = tab.T[blockIdx.y];
  const int tid = threadIdx.x;
  const int colg = tid & 63, seg = tid >> 6;
  const size_t c = ((size_t)blockIdx.x << 6) + colg;
  float m = -1e30f, s = 0.f;
  for (int n = seg; n < DIM2; n += 8) {
    float v = bf2f(T[(size_t)n * S_TOK + c]);
    float mn = fmaxf(m, v);
    s = s * __expf(m - mn) + __expf(v - mn);
    m = mn;
  }
  __shared__ float redm[512], reds[512];
  redm[tid] = m; reds[tid] = s;
  __syncthreads();
  if (seg == 0) {
    float M = m, S = s;
#pragma unroll
    for (int k = 1; k < 8; ++k) {
      float mk = redm[colg + (k << 6)], sk = reds[colg + (k << 6)];
      float mn = fmaxf(M, mk);
      S = S * __expf(M - mn) + sk * __expf(mk - mn);
      M = mn;
    }
    redm[colg] = M; reds[colg] = 1.0f / S;
  }
  __syncthreads();
  m = redm[colg];
  const float inv = reds[colg];
  for (int n = seg; n < DIM2; n += 8) {
    size_t idx = (size_t)n * S_TOK + c;
    T[idx] = f2bf(__expf(bf2f(T[idx]) - m) * inv);
  }
}

struct GPtr {
  const unsigned short* A[6];
  const unsigned short* Arow2[6];
  const unsigned short* B[6];
  const unsigned short* Bk2[6];
  const float* bias[6];
  void* C[6];
  int Ks[6];
  int ldas[6];
};
struct TPar { const unsigned short* src[2]; unsigned short* dst[2]; };

// ---------------- 128x128 single-buffer kernel (G4 + transposes, G5) ----------------
template <int BIAS_ROW, int OUT_BF16, int NZG>
__global__ __launch_bounds__(256, 3) void gemm_nt(GPtr p, TPar tp, int ldb, int ldc,
                                                  float scale, int do_relu) {
  __shared__ __align__(16) char lds[32768];
  const int z = blockIdx.z;
  const int tid  = threadIdx.x;

  if (NZG >= 0 && z >= NZG) {  // ---- transpose path ----
    const unsigned short* src = tp.src[z - NZG];
    unsigned short* dst = tp.dst[z - NZG];
    unsigned short* tl = (unsigned short*)lds;
    const int nblk = gridDim.x * gridDim.y;
    int bid = blockIdx.y * gridDim.x + blockIdx.x;
    for (int it = bid; it < (DIM2 / 64) * (S_TOK / 64); it += nblk) {
      int tx = it & (S_TOK / 64 - 1), ty = it >> 7;
      int r0 = ty << 6, c0 = tx << 6;
#pragma unroll
      for (int i = 0; i < 2; ++i) {
        int ch = tid + (i << 8);
        int r = ch >> 3, c8 = (ch & 7) << 3;
        s16x8 w = *(const s16x8*)(src + (size_t)(r0 + r) * S_TOK + c0 + c8);
        int sw = ((r ^ (r >> 3)) & 7) << 3;
        *(s16x8*)&tl[(r << 6) + (c8 ^ sw)] = w;
      }
      __syncthreads();
#pragma unroll
      for (int i = 0; i < 2; ++i) {
        int ch = tid + (i << 8);
        int c = ch >> 3, r8 = (ch & 7) << 3;
        s16x8 w;
#pragma unroll
        for (int j = 0; j < 8; ++j) {
          int rr = r8 + j;
          w[j] = (short)tl[(rr << 6) + (c ^ (((rr ^ (rr >> 3)) & 7) << 3))];
        }
        *(s16x8*)(dst + (size_t)(c0 + c) * DIM2 + r0 + r8) = w;
      }
      __syncthreads();
    }
    return;
  }

  char* As = lds;
  char* Bs = lds + 16384;
  const int lane = tid & 63;
  const int wave = tid >> 6;
  const int wm = (wave >> 1) << 6;
  const int wn = (wave & 1) << 6;
  const int m0 = blockIdx.y << 7;
  const int n0 = blockIdx.x << 7;
  const int lda = p.ldas[z];
  const int K = p.Ks[z];

  const unsigned short* Au = p.A[z];
  const unsigned short* B  = p.B[z];
  const float* bias = p.bias[z];
  void* Cv = p.C[z];

  int srow[4], sgk[4];
#pragma unroll
  for (int i = 0; i < 4; ++i) {
    int c = (wave << 8) + (i << 6) + lane;
    int row = c >> 3, kc = c & 7;
    srow[i] = row;
    sgk[i]  = (kc ^ ((row ^ (row >> 3)) & 7)) << 3;
  }

  f32x4 acc[4][4];
#pragma unroll
  for (int i = 0; i < 4; ++i)
#pragma unroll
    for (int j = 0; j < 4; ++j) acc[i][j] = {0.f, 0.f, 0.f, 0.f};

  for (int k0 = 0; k0 < K; k0 += 64) {
#pragma unroll
    for (int i = 0; i < 4; ++i) {
      char* dA = As + (((wave << 2) + i) << 10);
      char* dB = Bs + (((wave << 2) + i) << 10);
      gld_lds16(Au + (size_t)(m0 + srow[i]) * lda + k0 + sgk[i], dA);
      gld_lds16(B  + (size_t)(n0 + srow[i]) * ldb + k0 + sgk[i], dB);
    }
    __syncthreads();
#pragma unroll
    for (int ks = 0; ks < 2; ++ks) {
      bf16x8 af[4], bfr[4];
      int kk = (ks << 5) + ((lane >> 4) << 3);
#pragma unroll
      for (int t = 0; t < 4; ++t) {
        af[t]  = *(const bf16x8*)(As + lds_off(wm + (t << 4) + (lane & 15), kk));
        bfr[t] = *(const bf16x8*)(Bs + lds_off(wn + (t << 4) + (lane & 15), kk));
      }
#pragma unroll
      for (int mt = 0; mt < 4; ++mt)
#pragma unroll
        for (int nt = 0; nt < 4; ++nt)
          acc[mt][nt] = __builtin_amdgcn_mfma_f32_16x16x32_bf16(af[mt], bfr[nt], acc[mt][nt], 0, 0, 0);
    }
    __syncthreads();
  }

  if (OUT_BF16) {
    unsigned short* ct = (unsigned short*)lds;
    __syncthreads();
#pragma unroll
    for (int nt = 0; nt < 4; ++nt) {
      int cl = wn + (nt << 4) + (lane & 15);
      float bcol = (!BIAS_ROW && bias) ? bias[n0 + cl] : 0.0f;
#pragma unroll
      for (int mt = 0; mt < 4; ++mt) {
#pragma unroll
        for (int r = 0; r < 4; ++r) {
          int rl = wm + (mt << 4) + ((lane >> 4) << 2) + r;
          float bv = BIAS_ROW ? (bias ? bias[m0 + rl] : 0.0f) : bcol;
          float v = acc[mt][nt][r] * scale + bv;
          if (do_relu) v = fmaxf(v, 0.0f);
          ct[(rl << 7) + (cl ^ (((rl >> 2) & 3) << 4))] = f2bf(v);
        }
      }
    }
    __syncthreads();
#pragma unroll
    for (int it = 0; it < 8; ++it) {
      int c = (it << 8) + tid;
      int rl = c >> 4, co = (c & 15) << 3;
      s16x8 w = *(const s16x8*)(ct + (rl << 7) + (co ^ (((rl >> 2) & 3) << 4)));
      *(s16x8*)((unsigned short*)Cv + (size_t)(m0 + rl) * ldc + n0 + co) = w;
    }
  } else {
#pragma unroll
    for (int nt = 0; nt < 4; ++nt) {
      int col = n0 + wn + (nt << 4) + (lane & 15);
      float bcol = (!BIAS_ROW && bias) ? bias[col] : 0.0f;
#pragma unroll
      for (int mt = 0; mt < 4; ++mt) {
        f32x4 a = acc[mt][nt];
#pragma unroll
        for (int r = 0; r < 4; ++r) {
          int rowg = m0 + wm + (mt << 4) + ((lane >> 4) << 2) + r;
          float bv = BIAS_ROW ? (bias ? bias[rowg] : 0.0f) : bcol;
          float v = a[r] * scale + bv;
          if (do_relu) v = fmaxf(v, 0.0f);
          ((float*)Cv)[(size_t)rowg * ldc + col] = v;
        }
      }
    }
  }
}

// ---------------- 256x256 counted-vmcnt kernel (rect XCD, LDS epilogue) ----------
template <int ASPLIT, int BSPLIT, int BIAS_ROW, int OUT_BF16, int PHASES>
__global__ __launch_bounds__(512, 2) void gemm256(GPtr p, int ldb, int ldc,
                                                  float scale, int do_relu,
                                                  int RW, int XW) {
  __shared__ __align__(16) char lds[131072];
  const int z = blockIdx.z;
  const int tid  = threadIdx.x;
  const int lane = tid & 63;
  const int wave = tid >> 6;
  const int wm   = wave >> 2;
  const int wn   = wave & 3;
  const int lda  = p.ldas[z];
  const int K    = p.Ks[z];

  const int gx = gridDim.x;
  const int nper = (gx * gridDim.y) >> 3;
  const int RH = nper / RW;
  int bid = blockIdx.y * gx + blockIdx.x;
  int xcd = bid & 7, j = bid >> 3;
  const int n0 = (RW * (xcd % XW) + (j % RW)) << 8;
  const int m0 = (RH * (xcd / XW) + (j / RW)) << 8;

  const unsigned short* Au = p.A[z];
  int mb = m0;
  if (ASPLIT && m0 >= 2048) { Au = p.Arow2[z]; mb = m0 - 2048; }
  const unsigned short* Bp = p.B[z];
  const float* bias = p.bias[z];
  void* Cv = p.C[z];

  const int NT = K >> 6;

  int srow_[2], skel_[2];
#pragma unroll
  for (int i = 0; i < 2; ++i) {
    int row = (i << 7) + (wave << 4) + (lane >> 2);
    srow_[i] = row;
    skel_[i] = ((lane & 3) ^ ((row >> 1) & 3)) << 3;
  }
  const unsigned short* aB[2];
  const unsigned short* bB[2];
  const unsigned short* b2B[2];
#pragma unroll
  for (int i = 0; i < 2; ++i) {
    aB[i]  = Au + (size_t)(mb + srow_[i]) * lda + skel_[i];
    bB[i]  = Bp + (size_t)(n0 + srow_[i]) * ldb + skel_[i];
    b2B[i] = BSPLIT ? (p.Bk2[z] + (size_t)(n0 + srow_[i]) * ldb + skel_[i] - DIM)
                    : bB[i];
  }

  auto stage_unit = [&](int t, int u) {
    const int k0 = t << 6;
    const int h  = u >> 1;
    char* base = lds + ((t & 1) << 16) + ((u & 1) << 15) + (h << 14) + (wave << 10);
#pragma unroll
    for (int i = 0; i < 2; ++i) {
      const unsigned short* src;
      if (u & 1) src = ((BSPLIT && k0 >= DIM) ? b2B[i] : bB[i]) + k0 + (h << 5);
      else       src = aB[i] + k0 + (h << 5);
      gld_lds16(src, base + (i << 13));
    }
  };

  auto rdA = [&](const char* buf, int h, int mf) -> bf16x8 {
    int row = (wm << 7) + (mf << 4) + (lane & 15);
    int col = (lane >> 4) ^ ((row >> 1) & 3);
    return *(const bf16x8*)(buf + (h << 14) + (row << 6) + (col << 4));
  };
  auto rdB = [&](const char* buf, int h, int nf) -> bf16x8 {
    int row = (wn << 6) + (nf << 4) + (lane & 15);
    int col = (lane >> 4) ^ ((row >> 1) & 3);
    return *(const bf16x8*)(buf + 32768 + (h << 14) + (row << 6) + (col << 4));
  };

  f32x4 acc[8][4];
#pragma unroll
  for (int i = 0; i < 8; ++i)
#pragma unroll
    for (int j2 = 0; j2 < 4; ++j2) acc[i][j2] = {0.f, 0.f, 0.f, 0.f};

  stage_unit(0, 0); stage_unit(0, 1); stage_unit(0, 2); stage_unit(0, 3);

  for (int t = 0; t < NT; ++t) {
    const char* buf = lds + ((t & 1) << 16);
    const bool more = (t + 1 < NT);

    if (PHASES == 2) {
      bf16x8 aq[8], bq[4];
      if (more) {
        stage_unit(t + 1, 0); stage_unit(t + 1, 1);
        asm volatile("s_waitcnt vmcnt(8)" ::: "memory");
      } else {
        asm volatile("s_waitcnt vmcnt(4)" ::: "memory");
      }
      __builtin_amdgcn_s_barrier();
      __builtin_amdgcn_sched_barrier(0);
#pragma unroll
      for (int nf = 0; nf < 4; ++nf) bq[nf] = rdB(buf, 0, nf);
#pragma unroll
      for (int mf = 0; mf < 8; ++mf) aq[mf] = rdA(buf, 0, mf);
      __builtin_amdgcn_s_setprio(1);
#pragma unroll
      for (int mf = 0; mf < 8; ++mf)
#pragma unroll
        for (int nf = 0; nf < 4; ++nf)
          acc[mf][nf] = __builtin_amdgcn_mfma_f32_16x16x32_bf16(aq[mf], bq[nf], acc[mf][nf], 0, 0, 0);
      __builtin_amdgcn_s_setprio(0);
      __builtin_amdgcn_s_barrier();
      if (more) {
        stage_unit(t + 1, 2); stage_unit(t + 1, 3);
        asm volatile("s_waitcnt vmcnt(8)" ::: "memory");
      } else {
        asm volatile("s_waitcnt vmcnt(0)" ::: "memory");
      }
      __builtin_amdgcn_s_barrier();
      __builtin_amdgcn_sched_barrier(0);
#pragma unroll
      for (int nf = 0; nf < 4; ++nf) bq[nf] = rdB(buf, 1, nf);
#pragma unroll
      for (int mf = 0; mf < 8; ++mf) aq[mf] = rdA(buf, 1, mf);
      __builtin_amdgcn_s_setprio(1);
#pragma unroll
      for (int mf = 0; mf < 8; ++mf)
#pragma unroll
        for (int nf = 0; nf < 4; ++nf)
          acc[mf][nf] = __builtin_amdgcn_mfma_f32_16x16x32_bf16(aq[mf], bq[nf], acc[mf][nf], 0, 0, 0);
      __builtin_amdgcn_s_setprio(0);
      __builtin_amdgcn_s_barrier();
    } else {
      bf16x8 aq[4], bq[4];
      if (more) { stage_unit(t + 1, 0); asm volatile("s_waitcnt vmcnt(6)" ::: "memory"); }
      else      { asm volatile("s_waitcnt vmcnt(4)" ::: "memory"); }
      __builtin_amdgcn_s_barrier();
      __builtin_amdgcn_sched_barrier(0);
#pragma unroll
      for (int nf = 0; nf < 4; ++nf) bq[nf] = rdB(buf, 0, nf);
#pragma unroll
      for (int mf = 0; mf < 4; ++mf) aq[mf] = rdA(buf, 0, mf);
      __builtin_amdgcn_s_setprio(1);
#pragma unroll
      for (int mf = 0; mf < 4; ++mf)
#pragma unroll
        for (int nf = 0; nf < 4; ++nf)
          acc[mf][nf] = __builtin_amdgcn_mfma_f32_16x16x32_bf16(aq[mf], bq[nf], acc[mf][nf], 0, 0, 0);
      __builtin_amdgcn_s_setprio(0);
      __builtin_amdgcn_s_barrier();
#pragma unroll
      for (int mf = 0; mf < 4; ++mf) aq[mf] = rdA(buf, 0, mf + 4);
      if (more) stage_unit(t + 1, 1);
      __builtin_amdgcn_s_setprio(1);
#pragma unroll
      for (int mf = 0; mf < 4; ++mf)
#pragma unroll
        for (int nf = 0; nf < 4; ++nf)
          acc[mf + 4][nf] = __builtin_amdgcn_mfma_f32_16x16x32_bf16(aq[mf], bq[nf], acc[mf + 4][nf], 0, 0, 0);
      __builtin_amdgcn_s_setprio(0);
      __builtin_amdgcn_s_barrier();
      if (more) { stage_unit(t + 1, 2); asm volatile("s_waitcnt vmcnt(6)" ::: "memory"); }
      else      { asm volatile("s_waitcnt vmcnt(0)" ::: "memory"); }
      __builtin_amdgcn_s_barrier();
      __builtin_amdgcn_sched_barrier(0);
#pragma unroll
      for (int nf = 0; nf < 4; ++nf) bq[nf] = rdB(buf, 1, nf);
#pragma unroll
      for (int mf = 0; mf < 4; ++mf) aq[mf] = rdA(buf, 1, mf);
      __builtin_amdgcn_s_setprio(1);
#pragma unroll
      for (int mf = 0; mf < 4; ++mf)
#pragma unroll
        for (int nf = 0; nf < 4; ++nf)
          acc[mf][nf] = __builtin_amdgcn_mfma_f32_16x16x32_bf16(aq[mf], bq[nf], acc[mf][nf], 0, 0, 0);
      __builtin_amdgcn_s_setprio(0);
      __builtin_amdgcn_s_barrier();
#pragma unroll
      for (int mf = 0; mf < 4; ++mf) aq[mf] = rdA(buf, 1, mf + 4);
      if (more) stage_unit(t + 1, 3);
      __builtin_amdgcn_s_setprio(1);
#pragma unroll
      for (int mf = 0; mf < 4; ++mf)
#pragma unroll
        for (int nf = 0; nf < 4; ++nf)
          acc[mf + 4][nf] = __builtin_amdgcn_mfma_f32_16x16x32_bf16(aq[mf], bq[nf], acc[mf + 4][nf], 0, 0, 0);
      __builtin_amdgcn_s_setprio(0);
      __builtin_amdgcn_s_barrier();
    }
  }

  __syncthreads();
  if (OUT_BF16) {
    unsigned short* ct = (unsigned short*)lds;
#pragma unroll
    for (int nf = 0; nf < 4; ++nf) {
      int cl = (wn << 6) + (nf << 4) + (lane & 15);
      float bcol = (!BIAS_ROW && bias) ? bias[n0 + cl] : 0.0f;
#pragma unroll
      for (int mf = 0; mf < 8; ++mf) {
#pragma unroll
        for (int r = 0; r < 4; ++r) {
          int rl = (wm << 7) + (mf << 4) + ((lane >> 4) << 2) + r;
          float bv = BIAS_ROW ? (bias ? bias[m0 + rl] : 0.0f) : bcol;
          float v = acc[mf][nf][r] * scale + bv;
          if (do_relu) v = fmaxf(v, 0.0f);
          ct[(rl << 8) + (cl ^ (((rl >> 2) & 3) << 4))] = f2bf(v);
        }
      }
    }
    __syncthreads();
#pragma unroll
    for (int it = 0; it < 16; ++it) {
      int c = (it << 9) + tid;
      int rl = c >> 5, co = (c & 31) << 3;
      s16x8 w = *(const s16x8*)(ct + (rl << 8) + (co ^ (((rl >> 2) & 3) << 4)));
      *(s16x8*)((unsigned short*)Cv + (size_t)(m0 + rl) * ldc + n0 + co) = w;
    }
  } else {
    float* ctf = (float*)lds;
#pragma unroll
    for (int h = 0; h < 2; ++h) {
      if (h) __syncthreads();
      if (wm == h) {
#pragma unroll
        for (int nf = 0; nf < 4; ++nf) {
          int cl = (wn << 6) + (nf << 4) + (lane & 15);
          float bcol = (!BIAS_ROW && bias) ? bias[n0 + cl] : 0.0f;
#pragma unroll
          for (int mf = 0; mf < 8; ++mf) {
#pragma unroll
            for (int r = 0; r < 4; ++r) {
              int rl2 = (mf << 4) + ((lane >> 4) << 2) + r;
              float bv = BIAS_ROW ? (bias ? bias[m0 + (h << 7) + rl2] : 0.0f) : bcol;
              float v = acc[mf][nf][r] * scale + bv;
              if (do_relu) v = fmaxf(v, 0.0f);
              ctf[(rl2 << 8) + (cl ^ (((rl2 >> 2) & 3) << 3))] = v;
            }
          }
        }
      }
      __syncthreads();
#pragma unroll
      for (int it = 0; it < 16; ++it) {
        int c = (it << 9) + tid;
        int rl2 = c >> 6, co = (c & 63) << 2;
        float4 w = *(const float4*)(ctf + (rl2 << 8) + (co ^ (((rl2 >> 2) & 3) << 3)));
        *(float4*)((float*)Cv + (size_t)(m0 + (h << 7) + rl2) * ldc + n0 + co) = w;
      }
    }
  }
}

// ---------------- 128x128 double-buffered counted-vmcnt kernel, 2 blocks/CU ------
// Shrink of gemm256: BM=BN=128, BK=64, 4 waves (2m x 2n), acc[4][4], LDS 64KB
// (2 x 32KB K-tile buffers), PHASES=2 schedule with identical vmcnt accounting
// (2 loads/unit/thread). 2 blocks/CU -> independent barrier domains overlap.
template <int ASPLIT, int BSPLIT, int BIAS_ROW, int OUT_BF16>
__global__ __launch_bounds__(256, 2) void gemm128(GPtr p, int ldb, int ldc,
                                                  float scale, int do_relu,
                                                  int RW, int XW) {
  __shared__ __align__(16) char lds[65536];
  const int z = blockIdx.z;
  const int tid  = threadIdx.x;
  const int lane = tid & 63;
  const int wave = tid >> 6;    // 0..3
  const int wm   = wave >> 1;   // 0..1
  const int wn   = wave & 1;    // 0..1
  const int lda  = p.ldas[z];
  const int K    = p.Ks[z];

  // rectangle XCD partition (bijective: RW*XW == gx)
  const int gx = gridDim.x;
  const int nper = (gx * gridDim.y) >> 3;
  const int RH = nper / RW;
  int bid = blockIdx.y * gx + blockIdx.x;
  int xcd = bid & 7, j = bid >> 3;
  const int n0 = (RW * (xcd % XW) + (j % RW)) << 7;
  const int m0 = (RH * (xcd / XW) + (j / RW)) << 7;

  const unsigned short* Au = p.A[z];
  int mb = m0;
  if (ASPLIT && m0 >= 2048) { Au = p.Arow2[z]; mb = m0 - 2048; }
  const unsigned short* Bp = p.B[z];
  const float* bias = p.bias[z];
  void* Cv = p.C[z];

  const int NT = K >> 6;

  // unit = 8KB = 512 chunks (128 rows x 32 k); 2 chunks/thread.
  int srow_[2], skel_[2];
#pragma unroll
  for (int i = 0; i < 2; ++i) {
    int row = (i << 6) + (wave << 4) + (lane >> 2);
    srow_[i] = row;
    skel_[i] = ((lane & 3) ^ ((row >> 1) & 3)) << 3;
  }
  const unsigned short* aB[2];
  const unsigned short* bB[2];
  const unsigned short* b2B[2];
#pragma unroll
  for (int i = 0; i < 2; ++i) {
    aB[i]  = Au + (size_t)(mb + srow_[i]) * lda + skel_[i];
    bB[i]  = Bp + (size_t)(n0 + srow_[i]) * ldb + skel_[i];
    b2B[i] = BSPLIT ? (p.Bk2[z] + (size_t)(n0 + srow_[i]) * ldb + skel_[i] - DIM)
                    : bB[i];
  }

  auto stage_unit = [&](int t, int u) {
    const int k0 = t << 6;
    const int h  = u >> 1;
    char* base = lds + ((t & 1) << 15) + ((u & 1) << 14) + (h << 13) + (wave << 10);
#pragma unroll
    for (int i = 0; i < 2; ++i) {
      const unsigned short* src;
      if (u & 1) src = ((BSPLIT && k0 >= DIM) ? b2B[i] : bB[i]) + k0 + (h << 5);
      else       src = aB[i] + k0 + (h << 5);
      gld_lds16(src, base + (i << 12));
    }
  };

  auto rdA = [&](const char* buf, int h, int mf) -> bf16x8 {
    int row = (wm << 6) + (mf << 4) + (lane & 15);
    int col = (lane >> 4) ^ ((row >> 1) & 3);
    return *(const bf16x8*)(buf + (h << 13) + (row << 6) + (col << 4));
  };
  auto rdB = [&](const char* buf, int h, int nf) -> bf16x8 {
    int row = (wn << 6) + (nf << 4) + (lane & 15);
    int col = (lane >> 4) ^ ((row >> 1) & 3);
    return *(const bf16x8*)(buf + 16384 + (h << 13) + (row << 6) + (col << 4));
  };

  f32x4 acc[4][4];
#pragma unroll
  for (int i = 0; i < 4; ++i)
#pragma unroll
    for (int j2 = 0; j2 < 4; ++j2) acc[i][j2] = {0.f, 0.f, 0.f, 0.f};

  stage_unit(0, 0); stage_unit(0, 1); stage_unit(0, 2); stage_unit(0, 3);

  for (int t = 0; t < NT; ++t) {
    const char* buf = lds + ((t & 1) << 15);
    const bool more = (t + 1 < NT);
    bf16x8 aq[4], bq[4];
    // ---- phase A: k-half 0 ----
    if (more) {
      stage_unit(t + 1, 0); stage_unit(t + 1, 1);
      asm volatile("s_waitcnt vmcnt(8)" ::: "memory");
    } else {
      asm volatile("s_waitcnt vmcnt(4)" ::: "memory");
    }
    __builtin_amdgcn_s_barrier();
    __builtin_amdgcn_sched_barrier(0);
#pragma unroll
    for (int nf = 0; nf < 4; ++nf) bq[nf] = rdB(buf, 0, nf);
#pragma unroll
    for (int mf = 0; mf < 4; ++mf) aq[mf] = rdA(buf, 0, mf);
    __builtin_amdgcn_s_setprio(1);
#pragma unroll
    for (int mf = 0; mf < 4; ++mf)
#pragma unroll
      for (int nf = 0; nf < 4; ++nf)
        acc[mf][nf] = __builtin_amdgcn_mfma_f32_16x16x32_bf16(aq[mf], bq[nf], acc[mf][nf], 0, 0, 0);
    __builtin_amdgcn_s_setprio(0);
    __builtin_amdgcn_s_barrier();
    // ---- phase B: k-half 1 ----
    if (more) {
      stage_unit(t + 1, 2); stage_unit(t + 1, 3);
      asm volatile("s_waitcnt vmcnt(8)" ::: "memory");
    } else {
      asm volatile("s_waitcnt vmcnt(0)" ::: "memory");
    }
    __builtin_amdgcn_s_barrier();
    __builtin_amdgcn_sched_barrier(0);
#pragma unroll
    for (int nf = 0; nf < 4; ++nf) bq[nf] = rdB(buf, 1, nf);
#pragma unroll
    for (int mf = 0; mf < 4; ++mf) aq[mf] = rdA(buf, 1, mf);
    __builtin_amdgcn_s_setprio(1);
#pragma unroll
    for (int mf = 0; mf < 4; ++mf)
#pragma unroll
      for (int nf = 0; nf < 4; ++nf)
        acc[mf][nf] = __builtin_amdgcn_mfma_f32_16x16x32_bf16(aq[mf], bq[nf], acc[mf][nf], 0, 0, 0);
    __builtin_amdgcn_s_setprio(0);
    __builtin_amdgcn_s_barrier();
  }

  // ---- LDS-staged epilogue (64KB dbuf dead) ----
  __syncthreads();
  if (OUT_BF16) {
    unsigned short* ct = (unsigned short*)lds;  // 128x128 bf16 = 32KB
#pragma unroll
    for (int nf = 0; nf < 4; ++nf) {
      int cl = (wn << 6) + (nf << 4) + (lane & 15);
      float bcol = (!BIAS_ROW && bias) ? bias[n0 + cl] : 0.0f;
#pragma unroll
      for (int mf = 0; mf < 4; ++mf) {
#pragma unroll
        for (int r = 0; r < 4; ++r) {
          int rl = (wm << 6) + (mf << 4) + ((lane >> 4) << 2) + r;
          float bv = BIAS_ROW ? (bias ? bias[m0 + rl] : 0.0f) : bcol;
          float v = acc[mf][nf][r] * scale + bv;
          if (do_relu) v = fmaxf(v, 0.0f);
          ct[(rl << 7) + (cl ^ (((rl >> 2) & 3) << 4))] = f2bf(v);
        }
      }
    }
    __syncthreads();
#pragma unroll
    for (int it = 0; it < 8; ++it) {
      int c = (it << 8) + tid;
      int rl = c >> 4, co = (c & 15) << 3;
      s16x8 w = *(const s16x8*)(ct + (rl << 7) + (co ^ (((rl >> 2) & 3) << 4)));
      *(s16x8*)((unsigned short*)Cv + (size_t)(m0 + rl) * ldc + n0 + co) = w;
    }
  } else {
    float* ctf = (float*)lds;  // 128x128 f32 = 64KB, one pass (<=4-way scatter ok)
#pragma unroll
    for (int nf = 0; nf < 4; ++nf) {
      int cl = (wn << 6) + (nf << 4) + (lane & 15);
      float bcol = (!BIAS_ROW && bias) ? bias[n0 + cl] : 0.0f;
#pragma unroll
      for (int mf = 0; mf < 4; ++mf) {
#pragma unroll
        for (int r = 0; r < 4; ++r) {
          int rl = (wm << 6) + (mf << 4) + ((lane >> 4) << 2) + r;
          float bv = BIAS_ROW ? (bias ? bias[m0 + rl] : 0.0f) : bcol;
          float v = acc[mf][nf][r] * scale + bv;
          if (do_relu) v = fmaxf(v, 0.0f);
          ctf[(rl << 7) + cl] = v;
        }
      }
    }
    __syncthreads();
#pragma unroll
    for (int it = 0; it < 16; ++it) {
      int c = (it << 8) + tid;
      int rl = c >> 5, co = (c & 31) << 2;
      float4 w = *(const float4*)(ctf + (rl << 7) + co);
      *(float4*)((float*)Cv + (size_t)(m0 + rl) * ldc + n0 + co) = w;
    }
  }
}

extern "C" void kernel_launch(void* const* d_in, const int* in_sizes, int n_in,
                              void* d_out, int out_size, void* d_ws, size_t ws_size,
                              hipStream_t stream) {
  const float* X   = (const float*)d_in[0];
  const float* Y   = (const float*)d_in[1];
  const float* R   = (const float*)d_in[2];
  const float* Wi  = (const float*)d_in[3];
  const float* bi  = (const float*)d_in[4];
  const float* Wo  = (const float*)d_in[5];
  const float* bo  = (const float*)d_in[6];
  const float* Wc  = (const float*)d_in[7];
  const float* bc  = (const float*)d_in[8];
  const float* Wf  = (const float*)d_in[9];
  const float* bf_ = (const float*)d_in[10];
  float* out = (float*)d_out;

  char* ws = (char*)d_ws;
  size_t off = 0;
  auto alloc = [&](size_t b) { char* p = ws + off; off += (b + 255) & ~(size_t)255; return p; };
  unsigned short* Xb   = (unsigned short*)alloc((size_t)S_TOK * DIM  * 2);
  unsigned short* Yb   = (unsigned short*)alloc((size_t)S_TOK * DIM  * 2);
  unsigned short* Rb   = (unsigned short*)alloc((size_t)S_TOK * DIM  * 2);
  unsigned short* WiT  = (unsigned short*)alloc((size_t)DIM2 * DIM  * 2);
  unsigned short* WoT  = (unsigned short*)alloc((size_t)DIM2 * DIM  * 2);
  unsigned short* WcT  = (unsigned short*)alloc((size_t)DIM2 * DIM2 * 2);
  unsigned short* WfT  = (unsigned short*)alloc((size_t)OUTN * DIM2 * 2);
  unsigned short* iqT  = (unsigned short*)alloc((size_t)DIM2 * S_TOK * 2);
  unsigned short* oqT0 = (unsigned short*)alloc((size_t)DIM2 * S_TOK * 2);
  unsigned short* oqT1 = (unsigned short*)alloc((size_t)DIM2 * S_TOK * 2);
  unsigned short* icmT0= (unsigned short*)alloc((size_t)DIM2 * S_TOK * 2);
  unsigned short* icmT1= (unsigned short*)alloc((size_t)DIM2 * S_TOK * 2);
  unsigned short* iqk0 = Xb;
  unsigned short* oqk0 = Xb + (size_t)DIM2*DIM2;
  unsigned short* iqk1 = Yb;
  unsigned short* oqk1 = Yb + (size_t)DIM2*DIM2;
  unsigned short* meta0= iqT;
  unsigned short* meta1= iqT + (size_t)DIM2*DIM2;
  unsigned short* MWT0 = iqT + (size_t)2*DIM2*DIM2;
  unsigned short* MWT1 = iqT + (size_t)2*DIM2*DIM2 + (size_t)OUTN*DIM2;
  unsigned short* icm0 = oqT0;
  unsigned short* icm1 = oqT1;

  // PREP
  {
    PrepTab t{};
    t.in[0] = X; t.in[1] = Y; t.in[2] = R;
    t.out[0] = Xb; t.out[1] = Yb; t.out[2] = Rb;
    t.win[0] = Wi; t.wout[0] = WiT; t.R[0] = DIM;  t.C[0] = DIM2;
    t.win[1] = Wo; t.wout[1] = WoT; t.R[1] = DIM;  t.C[1] = DIM2;
    t.win[2] = Wc; t.wout[2] = WcT; t.R[2] = DIM2; t.C[2] = DIM2;
    t.win[3] = Wf; t.wout[3] = WfT; t.R[3] = DIM2; t.C[3] = OUTN;
    prep_all<<<dim3((S_TOK * DIM / 4) / 256, 1, 4), 256, 0, stream>>>(t);
  }

  const float rscale = 0.022097086912079608f;  // 1/sqrt(2048)

  // G12 via gemm128 (2 blocks/CU): long-K slices first
  {
    GPtr g{};
    g.A[0] = WcT; g.B[0] = Xb; g.Bk2[0] = Yb; g.bias[0] = bc; g.C[0] = icmT0;
    g.Ks[0] = DIM2; g.ldas[0] = DIM2;
    g.A[1] = WcT; g.B[1] = Xb; g.Bk2[1] = Rb; g.bias[1] = bc; g.C[1] = icmT1;
    g.Ks[1] = DIM2; g.ldas[1] = DIM2;
    g.A[2] = WiT; g.B[2] = Xb; g.Bk2[2] = Xb; g.bias[2] = bi; g.C[2] = iqT;
    g.Ks[2] = DIM; g.ldas[2] = DIM;
    g.A[3] = WoT; g.B[3] = Yb; g.Bk2[3] = Yb; g.bias[3] = bo; g.C[3] = oqT0;
    g.Ks[3] = DIM; g.ldas[3] = DIM;
    g.A[4] = WoT; g.B[4] = Rb; g.Bk2[4] = Rb; g.bias[4] = bo; g.C[4] = oqT1;
    g.Ks[4] = DIM; g.ldas[4] = DIM;
    gemm128<0,1,1,1><<<dim3(S_TOK/128, DIM2/128, 5), 256, 0, stream>>>(
        g, DIM, S_TOK, 1.f, 0, /*RW=*/8, /*XW=*/8);
  }
  // SM
  {
    SmTab st{};
    st.T[0] = iqT; st.T[1] = oqT0; st.T[2] = oqT1; st.T[3] = icmT0; st.T[4] = icmT1;
    softmax_cols<<<dim3(S_TOK / 64, 5), dim3(512), 0, stream>>>(st);
  }
  // G3: gemm256 PHASES=4 (measured best)
  {
    GPtr g{};
    g.A[0] = iqT; g.A[1] = iqT;
    g.Arow2[0] = oqT0; g.Arow2[1] = oqT1;
    g.B[0] = icmT0; g.B[1] = icmT1;
    g.C[0] = iqk0; g.C[1] = iqk1;
    g.Ks[0] = S_TOK; g.Ks[1] = S_TOK;
    g.ldas[0] = S_TOK; g.ldas[1] = S_TOK;
    gemm256<1,0,0,1,4><<<dim3(DIM2/256, 4096/256, 2), 512, 0, stream>>>(
        g, S_TOK, DIM2, 1.f, 0, /*RW=*/4, /*XW=*/2);
  }
  // G4 + T
  {
    GPtr g{};
    g.A[0] = iqk0; g.B[0] = oqk0; g.C[0] = meta0; g.Ks[0] = DIM2; g.ldas[0] = DIM2;
    g.A[1] = iqk1; g.B[1] = oqk1; g.C[1] = meta1; g.Ks[1] = DIM2; g.ldas[1] = DIM2;
    TPar tp{};
    tp.src[0] = icmT0; tp.dst[0] = icm0;
    tp.src[1] = icmT1; tp.dst[1] = icm1;
    gemm_nt<0,1,2><<<dim3(DIM2/128, DIM2/128, 4), 256, 0, stream>>>(
        g, tp, DIM2, DIM2, 1.f, 1);
  }
  // G5
  {
    GPtr g{};
    g.A[0] = WfT; g.B[0] = meta0; g.C[0] = MWT0; g.Ks[0] = DIM2; g.ldas[0] = DIM2;
    g.A[1] = WfT; g.B[1] = meta1; g.C[1] = MWT1; g.Ks[1] = DIM2; g.ldas[1] = DIM2;
    TPar tp{};
    gemm_nt<0,1,2><<<dim3(DIM2/128, OUTN/128, 2), 256, 0, stream>>>(
        g, tp, DIM2, DIM2, rscale, 0);
  }
  // G6: gemm256 PHASES=4, f32 out
  {
    GPtr g{};
    g.A[0] = icm0; g.B[0] = MWT0; g.bias[0] = bf_; g.C[0] = out;
    g.Ks[0] = DIM2; g.ldas[0] = DIM2;
    g.A[1] = icm1; g.B[1] = MWT1; g.bias[1] = bf_;
    g.C[1] = out + (size_t)S_TOK * OUTN;
    g.Ks[1] = DIM2; g.ldas[1] = DIM2;
    gemm256<0,0,0,0,4><<<dim3(OUTN/256, S_TOK/256, 2), 512, 0, stream>>>(
        g, DIM2, OUTN, 1.f, 1, /*RW=*/4, /*XW=*/1);
  }
  (void)in_sizes; (void)n_in; (void)out_size; (void)ws_size;
}

// Round 18
// 872.137 us; speedup vs baseline: 1.0262x; 1.0262x over previous
//
#include <hip/hip_runtime.h>

#define S_TOK 8192
#define DIM   1024
#define DIM2  2048
#define OUTN  1024

typedef __bf16 bf16x8 __attribute__((ext_vector_type(8)));
typedef float  f32x4  __attribute__((ext_vector_type(4)));
typedef short  s16x8  __attribute__((ext_vector_type(8)));
typedef unsigned short u16x4 __attribute__((ext_vector_type(4)));

__device__ __forceinline__ unsigned short f2bf(float x) {
  unsigned u = __builtin_bit_cast(unsigned, x);
  u = (u + 0x7FFFu + ((u >> 16) & 1u)) >> 16;
  return (unsigned short)u;
}
__device__ __forceinline__ float bf2f(unsigned short u) {
  return __builtin_bit_cast(float, (unsigned)u << 16);
}

__device__ __forceinline__ void gld_lds16(const void* g, void* l) {
  auto* g1 = reinterpret_cast<__attribute__((address_space(1))) unsigned*>(
      (unsigned long long)g);
  auto* l3 = reinterpret_cast<__attribute__((address_space(3))) unsigned*>(
      (unsigned long long)l);
  __builtin_amdgcn_global_load_lds(g1, l3, 16, 0, 0);
}

// 128^2-kernel swizzle for [rows][64] bf16 tiles (row stride 128B).
__device__ __forceinline__ int lds_off(int idx, int k) {
  int b = (idx << 7) + (k << 1);
  b ^= ((idx ^ (idx >> 3)) & 7) << 4;
  return b;
}

// ---- merged prep: z0-2 = f32->bf16 cvt; z3 = all 4 weight transposes ----
struct PrepTab {
  const float* in[3]; unsigned short* out[3];
  const float* win[4]; unsigned short* wout[4]; int R[4]; int C[4];
};
__global__ __launch_bounds__(256) void prep_all(PrepTab t) {
  __shared__ unsigned short tl[64 * 64];
  const int tid = threadIdx.x;
  if (blockIdx.z < 3) {
    const float* in = t.in[blockIdx.z];
    unsigned short* out = t.out[blockIdx.z];
    int i = blockIdx.x * 256 + tid;
    float4 v = ((const float4*)in)[i];
    u16x4 o;
    o[0] = f2bf(v.x); o[1] = f2bf(v.y); o[2] = f2bf(v.z); o[3] = f2bf(v.w);
    *(u16x4*)(out + (size_t)i * 4) = o;
    return;
  }
  int x = blockIdx.x;
  if (x >= 4096) return;
  int wz = x >> 10, rem = x & 1023, bx = rem & 31, by = rem >> 5;
  const int R = t.R[wz], C = t.C[wz];
  const int r0 = by << 6, c0 = bx << 6;
  if (r0 >= R || c0 >= C) return;
  const float* in = t.win[wz];
  unsigned short* out = t.wout[wz];
#pragma unroll
  for (int i = 0; i < 2; ++i) {
    int ch = tid + (i << 8);
    int r = ch >> 3, c8 = (ch & 7) << 3;
    const float* p = in + (size_t)(r0 + r) * C + c0 + c8;
    float4 a = *(const float4*)p, b = *(const float4*)(p + 4);
    s16x8 w;
    w[0] = (short)f2bf(a.x); w[1] = (short)f2bf(a.y);
    w[2] = (short)f2bf(a.z); w[3] = (short)f2bf(a.w);
    w[4] = (short)f2bf(b.x); w[5] = (short)f2bf(b.y);
    w[6] = (short)f2bf(b.z); w[7] = (short)f2bf(b.w);
    int sw = ((r ^ (r >> 3)) & 7) << 3;
    *(s16x8*)&tl[(r << 6) + (c8 ^ sw)] = w;
  }
  __syncthreads();
#pragma unroll
  for (int i = 0; i < 2; ++i) {
    int ch = tid + (i << 8);
    int c = ch >> 3, r8 = (ch & 7) << 3;
    s16x8 w;
#pragma unroll
    for (int j = 0; j < 8; ++j) {
      int rr = r8 + j;
      w[j] = (short)tl[(rr << 6) + (c ^ (((rr ^ (rr >> 3)) & 7) << 3))];
    }
    *(s16x8*)(out + (size_t)(c0 + c) * R + r0 + r8) = w;
  }
}

// Softmax over the ROW axis (2048 feats) of T [2048, S_TOK], per column, in place.
struct SmTab { unsigned short* T[6]; };
__global__ __launch_bounds__(512) void softmax_cols(SmTab tab) {
  unsigned short* T = tab.T[blockIdx.y];
  const int tid = threadIdx.x;
  const int colg = tid & 63, seg = tid >> 6;
  const size_t c = ((size_t)blockIdx.x << 6) + colg;
  float m = -1e30f, s = 0.f;
  for (int n = seg; n < DIM2; n += 8) {
    float v = bf2f(T[(size_t)n * S_TOK + c]);
    float mn = fmaxf(m, v);
    s = s * __expf(m - mn) + __expf(v - mn);
    m = mn;
  }
  __shared__ float redm[512], reds[512];
  redm[tid] = m; reds[tid] = s;
  __syncthreads();
  if (seg == 0) {
    float M = m, S = s;
#pragma unroll
    for (int k = 1; k < 8; ++k) {
      float mk = redm[colg + (k << 6)], sk = reds[colg + (k << 6)];
      float mn = fmaxf(M, mk);
      S = S * __expf(M - mn) + sk * __expf(mk - mn);
      M = mn;
    }
    redm[colg] = M; reds[colg] = 1.0f / S;
  }
  __syncthreads();
  m = redm[colg];
  const float inv = reds[colg];
  for (int n = seg; n < DIM2; n += 8) {
    size_t idx = (size_t)n * S_TOK + c;
    T[idx] = f2bf(__expf(bf2f(T[idx]) - m) * inv);
  }
}

struct GPtr {
  const unsigned short* A[6];
  const unsigned short* Arow2[6];
  const unsigned short* B[6];
  const unsigned short* Bk2[6];
  const float* bias[6];
  void* C[6];
  int Ks[6];
  int ldas[6];
};
struct TPar { const unsigned short* src[2]; unsigned short* dst[2]; };

// ---------------- 128x128 kernel (G4 + piggyback transposes, G5) ----------------
template <int BIAS_ROW, int OUT_BF16, int NZG>
__global__ __launch_bounds__(256, 3) void gemm_nt(GPtr p, TPar tp, int ldb, int ldc,
                                                  float scale, int do_relu) {
  __shared__ __align__(16) char lds[32768];
  const int z = blockIdx.z;
  const int tid  = threadIdx.x;

  if (NZG >= 0 && z >= NZG) {  // ---- transpose path ----
    const unsigned short* src = tp.src[z - NZG];
    unsigned short* dst = tp.dst[z - NZG];
    unsigned short* tl = (unsigned short*)lds;
    const int nblk = gridDim.x * gridDim.y;
    int bid = blockIdx.y * gridDim.x + blockIdx.x;
    for (int it = bid; it < (DIM2 / 64) * (S_TOK / 64); it += nblk) {
      int tx = it & (S_TOK / 64 - 1), ty = it >> 7;
      int r0 = ty << 6, c0 = tx << 6;
#pragma unroll
      for (int i = 0; i < 2; ++i) {
        int ch = tid + (i << 8);
        int r = ch >> 3, c8 = (ch & 7) << 3;
        s16x8 w = *(const s16x8*)(src + (size_t)(r0 + r) * S_TOK + c0 + c8);
        int sw = ((r ^ (r >> 3)) & 7) << 3;
        *(s16x8*)&tl[(r << 6) + (c8 ^ sw)] = w;
      }
      __syncthreads();
#pragma unroll
      for (int i = 0; i < 2; ++i) {
        int ch = tid + (i << 8);
        int c = ch >> 3, r8 = (ch & 7) << 3;
        s16x8 w;
#pragma unroll
        for (int j = 0; j < 8; ++j) {
          int rr = r8 + j;
          w[j] = (short)tl[(rr << 6) + (c ^ (((rr ^ (rr >> 3)) & 7) << 3))];
        }
        *(s16x8*)(dst + (size_t)(c0 + c) * DIM2 + r0 + r8) = w;
      }
      __syncthreads();
    }
    return;
  }

  char* As = lds;
  char* Bs = lds + 16384;
  const int lane = tid & 63;
  const int wave = tid >> 6;
  const int wm = (wave >> 1) << 6;
  const int wn = (wave & 1) << 6;
  const int m0 = blockIdx.y << 7;
  const int n0 = blockIdx.x << 7;
  const int lda = p.ldas[z];
  const int K = p.Ks[z];

  const unsigned short* Au = p.A[z];
  const unsigned short* B  = p.B[z];
  const float* bias = p.bias[z];
  void* Cv = p.C[z];

  int srow[4], sgk[4];
#pragma unroll
  for (int i = 0; i < 4; ++i) {
    int c = (wave << 8) + (i << 6) + lane;
    int row = c >> 3, kc = c & 7;
    srow[i] = row;
    sgk[i]  = (kc ^ ((row ^ (row >> 3)) & 7)) << 3;
  }

  f32x4 acc[4][4];
#pragma unroll
  for (int i = 0; i < 4; ++i)
#pragma unroll
    for (int j = 0; j < 4; ++j) acc[i][j] = {0.f, 0.f, 0.f, 0.f};

  for (int k0 = 0; k0 < K; k0 += 64) {
#pragma unroll
    for (int i = 0; i < 4; ++i) {
      char* dA = As + (((wave << 2) + i) << 10);
      char* dB = Bs + (((wave << 2) + i) << 10);
      gld_lds16(Au + (size_t)(m0 + srow[i]) * lda + k0 + sgk[i], dA);
      gld_lds16(B  + (size_t)(n0 + srow[i]) * ldb + k0 + sgk[i], dB);
    }
    __syncthreads();
#pragma unroll
    for (int ks = 0; ks < 2; ++ks) {
      bf16x8 af[4], bfr[4];
      int kk = (ks << 5) + ((lane >> 4) << 3);
#pragma unroll
      for (int t = 0; t < 4; ++t) {
        af[t]  = *(const bf16x8*)(As + lds_off(wm + (t << 4) + (lane & 15), kk));
        bfr[t] = *(const bf16x8*)(Bs + lds_off(wn + (t << 4) + (lane & 15), kk));
      }
#pragma unroll
      for (int mt = 0; mt < 4; ++mt)
#pragma unroll
        for (int nt = 0; nt < 4; ++nt)
          acc[mt][nt] = __builtin_amdgcn_mfma_f32_16x16x32_bf16(af[mt], bfr[nt], acc[mt][nt], 0, 0, 0);
    }
    __syncthreads();
  }

  if (OUT_BF16) {
    unsigned short* ct = (unsigned short*)lds;
    __syncthreads();
#pragma unroll
    for (int nt = 0; nt < 4; ++nt) {
      int cl = wn + (nt << 4) + (lane & 15);
      float bcol = (!BIAS_ROW && bias) ? bias[n0 + cl] : 0.0f;
#pragma unroll
      for (int mt = 0; mt < 4; ++mt) {
#pragma unroll
        for (int r = 0; r < 4; ++r) {
          int rl = wm + (mt << 4) + ((lane >> 4) << 2) + r;
          float bv = BIAS_ROW ? (bias ? bias[m0 + rl] : 0.0f) : bcol;
          float v = acc[mt][nt][r] * scale + bv;
          if (do_relu) v = fmaxf(v, 0.0f);
          ct[(rl << 7) + (cl ^ (((rl >> 2) & 3) << 4))] = f2bf(v);
        }
      }
    }
    __syncthreads();
#pragma unroll
    for (int it = 0; it < 8; ++it) {
      int c = (it << 8) + tid;
      int rl = c >> 4, co = (c & 15) << 3;
      s16x8 w = *(const s16x8*)(ct + (rl << 7) + (co ^ (((rl >> 2) & 3) << 4)));
      *(s16x8*)((unsigned short*)Cv + (size_t)(m0 + rl) * ldc + n0 + co) = w;
    }
  } else {
#pragma unroll
    for (int nt = 0; nt < 4; ++nt) {
      int col = n0 + wn + (nt << 4) + (lane & 15);
      float bcol = (!BIAS_ROW && bias) ? bias[col] : 0.0f;
#pragma unroll
      for (int mt = 0; mt < 4; ++mt) {
        f32x4 a = acc[mt][nt];
#pragma unroll
        for (int r = 0; r < 4; ++r) {
          int rowg = m0 + wm + (mt << 4) + ((lane >> 4) << 2) + r;
          float bv = BIAS_ROW ? (bias ? bias[rowg] : 0.0f) : bcol;
          float v = a[r] * scale + bv;
          if (do_relu) v = fmaxf(v, 0.0f);
          ((float*)Cv)[(size_t)rowg * ldc + col] = v;
        }
      }
    }
  }
}

// ---------------- 256x256 counted-vmcnt kernel (rect XCD, LDS epilogue) ----------
template <int ASPLIT, int BSPLIT, int BIAS_ROW, int OUT_BF16, int PHASES>
__global__ __launch_bounds__(512, 2) void gemm256(GPtr p, int ldb, int ldc,
                                                  float scale, int do_relu,
                                                  int RW, int XW) {
  __shared__ __align__(16) char lds[131072];
  const int z = blockIdx.z;
  const int tid  = threadIdx.x;
  const int lane = tid & 63;
  const int wave = tid >> 6;
  const int wm   = wave >> 2;
  const int wn   = wave & 3;
  const int lda  = p.ldas[z];
  const int K    = p.Ks[z];

  const int gx = gridDim.x;
  const int nper = (gx * gridDim.y) >> 3;
  const int RH = nper / RW;
  int bid = blockIdx.y * gx + blockIdx.x;
  int xcd = bid & 7, j = bid >> 3;
  const int n0 = (RW * (xcd % XW) + (j % RW)) << 8;
  const int m0 = (RH * (xcd / XW) + (j / RW)) << 8;

  const unsigned short* Au = p.A[z];
  int mb = m0;
  if (ASPLIT && m0 >= 2048) { Au = p.Arow2[z]; mb = m0 - 2048; }
  const unsigned short* Bp = p.B[z];
  const float* bias = p.bias[z];
  void* Cv = p.C[z];

  const int NT = K >> 6;

  int srow_[2], skel_[2];
#pragma unroll
  for (int i = 0; i < 2; ++i) {
    int row = (i << 7) + (wave << 4) + (lane >> 2);
    srow_[i] = row;
    skel_[i] = ((lane & 3) ^ ((row >> 1) & 3)) << 3;
  }
  const unsigned short* aB[2];
  const unsigned short* bB[2];
  const unsigned short* b2B[2];
#pragma unroll
  for (int i = 0; i < 2; ++i) {
    aB[i]  = Au + (size_t)(mb + srow_[i]) * lda + skel_[i];
    bB[i]  = Bp + (size_t)(n0 + srow_[i]) * ldb + skel_[i];
    b2B[i] = BSPLIT ? (p.Bk2[z] + (size_t)(n0 + srow_[i]) * ldb + skel_[i] - DIM)
                    : bB[i];
  }

  auto stage_unit = [&](int t, int u) {
    const int k0 = t << 6;
    const int h  = u >> 1;
    char* base = lds + ((t & 1) << 16) + ((u & 1) << 15) + (h << 14) + (wave << 10);
#pragma unroll
    for (int i = 0; i < 2; ++i) {
      const unsigned short* src;
      if (u & 1) src = ((BSPLIT && k0 >= DIM) ? b2B[i] : bB[i]) + k0 + (h << 5);
      else       src = aB[i] + k0 + (h << 5);
      gld_lds16(src, base + (i << 13));
    }
  };

  auto rdA = [&](const char* buf, int h, int mf) -> bf16x8 {
    int row = (wm << 7) + (mf << 4) + (lane & 15);
    int col = (lane >> 4) ^ ((row >> 1) & 3);
    return *(const bf16x8*)(buf + (h << 14) + (row << 6) + (col << 4));
  };
  auto rdB = [&](const char* buf, int h, int nf) -> bf16x8 {
    int row = (wn << 6) + (nf << 4) + (lane & 15);
    int col = (lane >> 4) ^ ((row >> 1) & 3);
    return *(const bf16x8*)(buf + 32768 + (h << 14) + (row << 6) + (col << 4));
  };

  f32x4 acc[8][4];
#pragma unroll
  for (int i = 0; i < 8; ++i)
#pragma unroll
    for (int j2 = 0; j2 < 4; ++j2) acc[i][j2] = {0.f, 0.f, 0.f, 0.f};

  stage_unit(0, 0); stage_unit(0, 1); stage_unit(0, 2); stage_unit(0, 3);

  for (int t = 0; t < NT; ++t) {
    const char* buf = lds + ((t & 1) << 16);
    const bool more = (t + 1 < NT);

    if (PHASES == 2) {
      bf16x8 aq[8], bq[4];
      if (more) {
        stage_unit(t + 1, 0); stage_unit(t + 1, 1);
        asm volatile("s_waitcnt vmcnt(8)" ::: "memory");
      } else {
        asm volatile("s_waitcnt vmcnt(4)" ::: "memory");
      }
      __builtin_amdgcn_s_barrier();
      __builtin_amdgcn_sched_barrier(0);
#pragma unroll
      for (int nf = 0; nf < 4; ++nf) bq[nf] = rdB(buf, 0, nf);
#pragma unroll
      for (int mf = 0; mf < 8; ++mf) aq[mf] = rdA(buf, 0, mf);
      __builtin_amdgcn_s_setprio(1);
#pragma unroll
      for (int mf = 0; mf < 8; ++mf)
#pragma unroll
        for (int nf = 0; nf < 4; ++nf)
          acc[mf][nf] = __builtin_amdgcn_mfma_f32_16x16x32_bf16(aq[mf], bq[nf], acc[mf][nf], 0, 0, 0);
      __builtin_amdgcn_s_setprio(0);
      __builtin_amdgcn_s_barrier();
      if (more) {
        stage_unit(t + 1, 2); stage_unit(t + 1, 3);
        asm volatile("s_waitcnt vmcnt(8)" ::: "memory");
      } else {
        asm volatile("s_waitcnt vmcnt(0)" ::: "memory");
      }
      __builtin_amdgcn_s_barrier();
      __builtin_amdgcn_sched_barrier(0);
#pragma unroll
      for (int nf = 0; nf < 4; ++nf) bq[nf] = rdB(buf, 1, nf);
#pragma unroll
      for (int mf = 0; mf < 8; ++mf) aq[mf] = rdA(buf, 1, mf);
      __builtin_amdgcn_s_setprio(1);
#pragma unroll
      for (int mf = 0; mf < 8; ++mf)
#pragma unroll
        for (int nf = 0; nf < 4; ++nf)
          acc[mf][nf] = __builtin_amdgcn_mfma_f32_16x16x32_bf16(aq[mf], bq[nf], acc[mf][nf], 0, 0, 0);
      __builtin_amdgcn_s_setprio(0);
      __builtin_amdgcn_s_barrier();
    } else {
      bf16x8 aq[4], bq[4];
      if (more) { stage_unit(t + 1, 0); asm volatile("s_waitcnt vmcnt(6)" ::: "memory"); }
      else      { asm volatile("s_waitcnt vmcnt(4)" ::: "memory"); }
      __builtin_amdgcn_s_barrier();
      __builtin_amdgcn_sched_barrier(0);
#pragma unroll
      for (int nf = 0; nf < 4; ++nf) bq[nf] = rdB(buf, 0, nf);
#pragma unroll
      for (int mf = 0; mf < 4; ++mf) aq[mf] = rdA(buf, 0, mf);
      __builtin_amdgcn_s_setprio(1);
#pragma unroll
      for (int mf = 0; mf < 4; ++mf)
#pragma unroll
        for (int nf = 0; nf < 4; ++nf)
          acc[mf][nf] = __builtin_amdgcn_mfma_f32_16x16x32_bf16(aq[mf], bq[nf], acc[mf][nf], 0, 0, 0);
      __builtin_amdgcn_s_setprio(0);
      __builtin_amdgcn_s_barrier();
#pragma unroll
      for (int mf = 0; mf < 4; ++mf) aq[mf] = rdA(buf, 0, mf + 4);
      if (more) stage_unit(t + 1, 1);
      __builtin_amdgcn_s_setprio(1);
#pragma unroll
      for (int mf = 0; mf < 4; ++mf)
#pragma unroll
        for (int nf = 0; nf < 4; ++nf)
          acc[mf + 4][nf] = __builtin_amdgcn_mfma_f32_16x16x32_bf16(aq[mf], bq[nf], acc[mf + 4][nf], 0, 0, 0);
      __builtin_amdgcn_s_setprio(0);
      __builtin_amdgcn_s_barrier();
      if (more) { stage_unit(t + 1, 2); asm volatile("s_waitcnt vmcnt(6)" ::: "memory"); }
      else      { asm volatile("s_waitcnt vmcnt(0)" ::: "memory"); }
      __builtin_amdgcn_s_barrier();
      __builtin_amdgcn_sched_barrier(0);
#pragma unroll
      for (int nf = 0; nf < 4; ++nf) bq[nf] = rdB(buf, 1, nf);
#pragma unroll
      for (int mf = 0; mf < 4; ++mf) aq[mf] = rdA(buf, 1, mf);
      __builtin_amdgcn_s_setprio(1);
#pragma unroll
      for (int mf = 0; mf < 4; ++mf)
#pragma unroll
        for (int nf = 0; nf < 4; ++nf)
          acc[mf][nf] = __builtin_amdgcn_mfma_f32_16x16x32_bf16(aq[mf], bq[nf], acc[mf][nf], 0, 0, 0);
      __builtin_amdgcn_s_setprio(0);
      __builtin_amdgcn_s_barrier();
#pragma unroll
      for (int mf = 0; mf < 4; ++mf) aq[mf] = rdA(buf, 1, mf + 4);
      if (more) stage_unit(t + 1, 3);
      __builtin_amdgcn_s_setprio(1);
#pragma unroll
      for (int mf = 0; mf < 4; ++mf)
#pragma unroll
        for (int nf = 0; nf < 4; ++nf)
          acc[mf + 4][nf] = __builtin_amdgcn_mfma_f32_16x16x32_bf16(aq[mf], bq[nf], acc[mf + 4][nf], 0, 0, 0);
      __builtin_amdgcn_s_setprio(0);
      __builtin_amdgcn_s_barrier();
    }
  }

  __syncthreads();
  if (OUT_BF16) {
    unsigned short* ct = (unsigned short*)lds;
#pragma unroll
    for (int nf = 0; nf < 4; ++nf) {
      int cl = (wn << 6) + (nf << 4) + (lane & 15);
      float bcol = (!BIAS_ROW && bias) ? bias[n0 + cl] : 0.0f;
#pragma unroll
      for (int mf = 0; mf < 8; ++mf) {
#pragma unroll
        for (int r = 0; r < 4; ++r) {
          int rl = (wm << 7) + (mf << 4) + ((lane >> 4) << 2) + r;
          float bv = BIAS_ROW ? (bias ? bias[m0 + rl] : 0.0f) : bcol;
          float v = acc[mf][nf][r] * scale + bv;
          if (do_relu) v = fmaxf(v, 0.0f);
          ct[(rl << 8) + (cl ^ (((rl >> 2) & 3) << 4))] = f2bf(v);
        }
      }
    }
    __syncthreads();
#pragma unroll
    for (int it = 0; it < 16; ++it) {
      int c = (it << 9) + tid;
      int rl = c >> 5, co = (c & 31) << 3;
      s16x8 w = *(const s16x8*)(ct + (rl << 8) + (co ^ (((rl >> 2) & 3) << 4)));
      *(s16x8*)((unsigned short*)Cv + (size_t)(m0 + rl) * ldc + n0 + co) = w;
    }
  } else {
    float* ctf = (float*)lds;
#pragma unroll
    for (int h = 0; h < 2; ++h) {
      if (h) __syncthreads();
      if (wm == h) {
#pragma unroll
        for (int nf = 0; nf < 4; ++nf) {
          int cl = (wn << 6) + (nf << 4) + (lane & 15);
          float bcol = (!BIAS_ROW && bias) ? bias[n0 + cl] : 0.0f;
#pragma unroll
          for (int mf = 0; mf < 8; ++mf) {
#pragma unroll
            for (int r = 0; r < 4; ++r) {
              int rl2 = (mf << 4) + ((lane >> 4) << 2) + r;
              float bv = BIAS_ROW ? (bias ? bias[m0 + (h << 7) + rl2] : 0.0f) : bcol;
              float v = acc[mf][nf][r] * scale + bv;
              if (do_relu) v = fmaxf(v, 0.0f);
              ctf[(rl2 << 8) + (cl ^ (((rl2 >> 2) & 3) << 3))] = v;
            }
          }
        }
      }
      __syncthreads();
#pragma unroll
      for (int it = 0; it < 16; ++it) {
        int c = (it << 9) + tid;
        int rl2 = c >> 6, co = (c & 63) << 2;
        float4 w = *(const float4*)(ctf + (rl2 << 8) + (co ^ (((rl2 >> 2) & 3) << 3)));
        *(float4*)((float*)Cv + (size_t)(m0 + (h << 7) + rl2) * ldc + n0 + co) = w;
      }
    }
  }
}

extern "C" void kernel_launch(void* const* d_in, const int* in_sizes, int n_in,
                              void* d_out, int out_size, void* d_ws, size_t ws_size,
                              hipStream_t stream) {
  const float* X   = (const float*)d_in[0];
  const float* Y   = (const float*)d_in[1];
  const float* R   = (const float*)d_in[2];
  const float* Wi  = (const float*)d_in[3];
  const float* bi  = (const float*)d_in[4];
  const float* Wo  = (const float*)d_in[5];
  const float* bo  = (const float*)d_in[6];
  const float* Wc  = (const float*)d_in[7];
  const float* bc  = (const float*)d_in[8];
  const float* Wf  = (const float*)d_in[9];
  const float* bf_ = (const float*)d_in[10];
  float* out = (float*)d_out;

  char* ws = (char*)d_ws;
  size_t off = 0;
  auto alloc = [&](size_t b) { char* p = ws + off; off += (b + 255) & ~(size_t)255; return p; };
  unsigned short* Xb   = (unsigned short*)alloc((size_t)S_TOK * DIM  * 2);
  unsigned short* Yb   = (unsigned short*)alloc((size_t)S_TOK * DIM  * 2);
  unsigned short* Rb   = (unsigned short*)alloc((size_t)S_TOK * DIM  * 2);
  unsigned short* WiT  = (unsigned short*)alloc((size_t)DIM2 * DIM  * 2);
  unsigned short* WoT  = (unsigned short*)alloc((size_t)DIM2 * DIM  * 2);
  unsigned short* WcT  = (unsigned short*)alloc((size_t)DIM2 * DIM2 * 2);
  unsigned short* WfT  = (unsigned short*)alloc((size_t)OUTN * DIM2 * 2);
  unsigned short* iqT  = (unsigned short*)alloc((size_t)DIM2 * S_TOK * 2);
  unsigned short* oqT0 = (unsigned short*)alloc((size_t)DIM2 * S_TOK * 2);
  unsigned short* oqT1 = (unsigned short*)alloc((size_t)DIM2 * S_TOK * 2);
  unsigned short* icmT0= (unsigned short*)alloc((size_t)DIM2 * S_TOK * 2);
  unsigned short* icmT1= (unsigned short*)alloc((size_t)DIM2 * S_TOK * 2);
  unsigned short* iqk0 = Xb;
  unsigned short* oqk0 = Xb + (size_t)DIM2*DIM2;
  unsigned short* iqk1 = Yb;
  unsigned short* oqk1 = Yb + (size_t)DIM2*DIM2;
  unsigned short* meta0= iqT;
  unsigned short* meta1= iqT + (size_t)DIM2*DIM2;
  unsigned short* MWT0 = iqT + (size_t)2*DIM2*DIM2;
  unsigned short* MWT1 = iqT + (size_t)2*DIM2*DIM2 + (size_t)OUTN*DIM2;
  unsigned short* icm0 = oqT0;
  unsigned short* icm1 = oqT1;

  // PREP: cvt X/Y/R + all weight transposes, one dispatch
  {
    PrepTab t{};
    t.in[0] = X; t.in[1] = Y; t.in[2] = R;
    t.out[0] = Xb; t.out[1] = Yb; t.out[2] = Rb;
    t.win[0] = Wi; t.wout[0] = WiT; t.R[0] = DIM;  t.C[0] = DIM2;
    t.win[1] = Wo; t.wout[1] = WoT; t.R[1] = DIM;  t.C[1] = DIM2;
    t.win[2] = Wc; t.wout[2] = WcT; t.R[2] = DIM2; t.C[2] = DIM2;
    t.win[3] = Wf; t.wout[3] = WfT; t.R[3] = DIM2; t.C[3] = OUTN;
    prep_all<<<dim3((S_TOK * DIM / 4) / 256, 1, 4), 256, 0, stream>>>(t);
  }

  const float rscale = 0.022097086912079608f;  // 1/sqrt(2048)

  // G12 merged (long-K first), PHASES=2
  {
    GPtr g{};
    g.A[0] = WcT; g.B[0] = Xb; g.Bk2[0] = Yb; g.bias[0] = bc; g.C[0] = icmT0;
    g.Ks[0] = DIM2; g.ldas[0] = DIM2;
    g.A[1] = WcT; g.B[1] = Xb; g.Bk2[1] = Rb; g.bias[1] = bc; g.C[1] = icmT1;
    g.Ks[1] = DIM2; g.ldas[1] = DIM2;
    g.A[2] = WiT; g.B[2] = Xb; g.Bk2[2] = Xb; g.bias[2] = bi; g.C[2] = iqT;
    g.Ks[2] = DIM; g.ldas[2] = DIM;
    g.A[3] = WoT; g.B[3] = Yb; g.Bk2[3] = Yb; g.bias[3] = bo; g.C[3] = oqT0;
    g.Ks[3] = DIM; g.ldas[3] = DIM;
    g.A[4] = WoT; g.B[4] = Rb; g.Bk2[4] = Rb; g.bias[4] = bo; g.C[4] = oqT1;
    g.Ks[4] = DIM; g.ldas[4] = DIM;
    gemm256<0,1,1,1,2><<<dim3(S_TOK/256, DIM2/256, 5), 512, 0, stream>>>(
        g, DIM, S_TOK, 1.f, 0, /*RW=*/4, /*XW=*/8);
  }
  // SM: two-pass column softmax, all 5 maps
  {
    SmTab st{};
    st.T[0] = iqT; st.T[1] = oqT0; st.T[2] = oqT1; st.T[3] = icmT0; st.T[4] = icmT1;
    softmax_cols<<<dim3(S_TOK / 64, 5), dim3(512), 0, stream>>>(st);
  }
  // G3: PHASES=4
  {
    GPtr g{};
    g.A[0] = iqT; g.A[1] = iqT;
    g.Arow2[0] = oqT0; g.Arow2[1] = oqT1;
    g.B[0] = icmT0; g.B[1] = icmT1;
    g.C[0] = iqk0; g.C[1] = iqk1;
    g.Ks[0] = S_TOK; g.Ks[1] = S_TOK;
    g.ldas[0] = S_TOK; g.ldas[1] = S_TOK;
    gemm256<1,0,0,1,4><<<dim3(DIM2/256, 4096/256, 2), 512, 0, stream>>>(
        g, S_TOK, DIM2, 1.f, 0, /*RW=*/4, /*XW=*/2);
  }
  // G4 + T
  {
    GPtr g{};
    g.A[0] = iqk0; g.B[0] = oqk0; g.C[0] = meta0; g.Ks[0] = DIM2; g.ldas[0] = DIM2;
    g.A[1] = iqk1; g.B[1] = oqk1; g.C[1] = meta1; g.Ks[1] = DIM2; g.ldas[1] = DIM2;
    TPar tp{};
    tp.src[0] = icmT0; tp.dst[0] = icm0;
    tp.src[1] = icmT1; tp.dst[1] = icm1;
    gemm_nt<0,1,2><<<dim3(DIM2/128, DIM2/128, 4), 256, 0, stream>>>(
        g, tp, DIM2, DIM2, 1.f, 1);
  }
  // G5
  {
    GPtr g{};
    g.A[0] = WfT; g.B[0] = meta0; g.C[0] = MWT0; g.Ks[0] = DIM2; g.ldas[0] = DIM2;
    g.A[1] = WfT; g.B[1] = meta1; g.C[1] = MWT1; g.Ks[1] = DIM2; g.ldas[1] = DIM2;
    TPar tp{};
    gemm_nt<0,1,2><<<dim3(DIM2/128, OUTN/128, 2), 256, 0, stream>>>(
        g, tp, DIM2, DIM2, rscale, 0);
  }
  // G6: PHASES=4, f32 out
  {
    GPtr g{};
    g.A[0] = icm0; g.B[0] = MWT0; g.bias[0] = bf_; g.C[0] = out;
    g.Ks[0] = DIM2; g.ldas[0] = DIM2;
    g.A[1] = icm1; g.B[1] = MWT1; g.bias[1] = bf_;
    g.C[1] = out + (size_t)S_TOK * OUTN;
    g.Ks[1] = DIM2; g.ldas[1] = DIM2;
    gemm256<0,0,0,0,4><<<dim3(OUTN/256, S_TOK/256, 2), 512, 0, stream>>>(
        g, DIM2, OUTN, 1.f, 1, /*RW=*/4, /*XW=*/1);
  }
  (void)in_sizes; (void)n_in; (void)out_size; (void)ws_size;
}